// Round 5
// baseline (246.787 us; speedup 1.0000x reference)
//
#include <hip/hip_runtime.h>
#include <hip/hip_bf16.h>

using short8  = __attribute__((ext_vector_type(8))) short;
using ushort8 = __attribute__((ext_vector_type(8))) unsigned short;
using f32x4   = __attribute__((ext_vector_type(4))) float;

#define BM 256
#define BN 256
#define BK 64
#define NKT 4   // K = 256 = NKT * BK

__device__ inline void gload_lds16(const void* g, void* lds) {
    __builtin_amdgcn_global_load_lds(
        (const __attribute__((address_space(1))) void*)g,
        (__attribute__((address_space(3))) void*)lds, 16, 0, 0);
}

// Kernel 0: suffix-sum table ST[k][j] = sum_{q>=k} E[j][q].
__global__ __launch_bounds__(256) void suffix_kernel(const float* __restrict__ E,
                                                     float* __restrict__ ST, int m) {
    int j = blockIdx.x;
    int k = threadIdx.x;
    int lane = k & 63, w = k >> 6;
    __shared__ float wtot[4];
    float v = (k < m) ? E[(size_t)j * m + k] : 0.f;
    #pragma unroll
    for (int off = 1; off < 64; off <<= 1) {
        float o = __shfl_down(v, off);
        if (lane + off < 64) v += o;
    }
    if (lane == 0) wtot[w] = v;
    __syncthreads();
    float add = 0.f;
    #pragma unroll
    for (int w2 = 0; w2 < 4; ++w2)
        if (w2 > w) add += wtot[w2];
    v += add;
    if (k < m) ST[(size_t)k * m + j] = v;
}

// Kernel 1: per-row prep. 16 lanes per row (4 rows/wave) -> 3 shfl steps per row.
// Assumes m == 256, B % 16 == 0.
__global__ __launch_bounds__(256) void prep_kernel(
    const float* __restrict__ z, const float* __restrict__ t,
    const float* __restrict__ e, const float* __restrict__ log_tau,
    const float* __restrict__ E, const float* __restrict__ L,
    const float* __restrict__ ST,
    __hip_bfloat16* __restrict__ hz, __hip_bfloat16* __restrict__ hy,
    float* __restrict__ g, float* __restrict__ acc, unsigned* __restrict__ done,
    int B, int m)
{
    const int tid = threadIdx.x;
    const int row = blockIdx.x * 16 + (tid >> 4);
    const int sub = tid & 15;
    if (blockIdx.x == 0 && tid == 0) *done = 0u;

    float tv = t[row], ev = e[row];

    // searchsorted (side='left'): first idx with L[idx] >= t. Fixed 8-iteration trip.
    int lo = 0, hi = m;
    while (lo < hi) { int mid = (lo + hi) >> 1; if (L[mid] < tv) lo = mid + 1; else hi = mid; }
    int idx = lo;
    if (idx == 0) idx = 1;
    if (idx == m) idx = m - 1;

    float Llo = L[idx - 1], Lhi = L[idx];
    float w    = (tv - Llo) / (Lhi - Llo);
    float invd = 1.0f / (float)(m - idx);
    float invtau = expf(-0.5f * log_tau[0]);   // 1/sqrt(exp(log_tau))

    const int j0 = sub * 16;
    f32x4 zv[4], El4[4], Eh4[4], Sc4[4], yv[4];
    #pragma unroll
    for (int q = 0; q < 4; ++q) {
        zv[q]  = *(const f32x4*)&z [(size_t)row * m + j0 + q * 4];
        El4[q] = *(const f32x4*)&E [(size_t)(idx - 1) * m + j0 + q * 4];
        Eh4[q] = *(const f32x4*)&E [(size_t)idx * m + j0 + q * 4];
        Sc4[q] = *(const f32x4*)&ST[(size_t)idx * m + j0 + q * 4];
    }
    float ssy = 0.f, ssz = 0.f;
    #pragma unroll
    for (int q = 0; q < 4; ++q)
        #pragma unroll
        for (int p = 0; p < 4; ++p) {
            float yint = El4[q][p] + (Eh4[q][p] - El4[q][p]) * w;
            float ycen = Sc4[q][p] * invd;
            float y = yint * ev + ycen * (1.f - ev);
            yv[q][p] = y; ssy += y * y;
            ssz += zv[q][p] * zv[q][p];
        }
    #pragma unroll
    for (int off = 1; off < 16; off <<= 1) {
        ssy += __shfl_xor(ssy, off);
        ssz += __shfl_xor(ssz, off);
    }
    float sy = invtau / fmaxf(sqrtf(ssy), 1e-12f);
    float sz = invtau / fmaxf(sqrtf(ssz), 1e-12f);

    float gp = 0.f;
    ushort8 oy[2], oz[2];
    #pragma unroll
    for (int q = 0; q < 4; ++q)
        #pragma unroll
        for (int p = 0; p < 4; ++p) {
            float hyv = yv[q][p] * sy, hzv = zv[q][p] * sz;
            gp += hyv * hzv;
            __hip_bfloat16 hb = __float2bfloat16(hyv);
            __hip_bfloat16 zb = __float2bfloat16(hzv);
            oy[q >> 1][(q & 1) * 4 + p] = *reinterpret_cast<unsigned short*>(&hb);
            oz[q >> 1][(q & 1) * 4 + p] = *reinterpret_cast<unsigned short*>(&zb);
        }
    *(ushort8*)&hy[(size_t)row * m + j0]     = oy[0];
    *(ushort8*)&hy[(size_t)row * m + j0 + 8] = oy[1];
    *(ushort8*)&hz[(size_t)row * m + j0]     = oz[0];
    *(ushort8*)&hz[(size_t)row * m + j0 + 8] = oz[1];
    #pragma unroll
    for (int off = 1; off < 16; off <<= 1) gp += __shfl_xor(gp, off);
    if (sub == 0) { g[row] = gp; acc[row] = 0.f; }
}

// Kernel 2: fused sim = hz @ hy^T + exp + row partial sums + (last block) finalize.
// 256x256 tile, 8 waves (2M x 4N, per-wave 128x64), BK=64, dbuf 128KB LDS.
// Counted-vmcnt pipeline: prologue primes tiles 0,1; during tile t (t=1,2) stage
// tile t+1; per-tile waits vmcnt(W0/W1) -- never drains mid-loop.
__global__ __launch_bounds__(512, 2) void gemm_lse_kernel(
    const __hip_bfloat16* __restrict__ hz, const __hip_bfloat16* __restrict__ hy,
    float* __restrict__ row_acc, const float* __restrict__ gvec,
    float* __restrict__ out, unsigned* __restrict__ done, int Brows, int K)
{
    __shared__ __hip_bfloat16 As[2][BM * BK];
    __shared__ __hip_bfloat16 Bs[2][BN * BK];

    const int tid  = threadIdx.x;
    const int wid  = tid >> 6;
    const int lane = tid & 63;
    const int wm   = wid >> 2;   // 0..1
    const int wn   = wid & 3;    // 0..3

    int bx = blockIdx.x, by = blockIdx.y;
    if (gridDim.x == 32 && gridDim.y == 32) {
        int orig = by * 32 + bx;
        int xcd = orig & 7, pos = orig >> 3;
        by = (xcd << 2) | (pos & 3);
        bx = pos >> 2;
    }
    const int row0 = by * BM, col0 = bx * BN;

    f32x4 acc[8][4];
    #pragma unroll
    for (int i = 0; i < 8; ++i)
        #pragma unroll
        for (int j = 0; j < 4; ++j)
            acc[i][j] = (f32x4){0.f, 0.f, 0.f, 0.f};

    const int srow = tid >> 3;            // 0..63
    const int c8   = tid & 7;
    const int cg   = c8 ^ (srow & 7);     // inverse-swizzled source chunk (rule 21)
    const int lm   = lane & 15, lk = lane >> 4;

    // B staged first (4 loads), then A in quarter order {0,2,1,3} so that the
    // quarters read by phase 0 (rows wm*128+0..63 -> s=0 / s=2) are OLDEST.
#define STAGE_B(buf, kt)                                                          \
    do {                                                                          \
        _Pragma("unroll")                                                         \
        for (int s = 0; s < 4; ++s)                                               \
            gload_lds16(hy + (size_t)(col0 + s * 64 + srow) * K + (kt) * BK + cg * 8, \
                        (void*)&Bs[buf][s * 4096 + wid * 512]);                   \
    } while (0)
#define STAGE_A(buf, kt)                                                          \
    do {                                                                          \
        const int sord[4] = {0, 2, 1, 3};                                         \
        _Pragma("unroll")                                                         \
        for (int si = 0; si < 4; ++si) {                                          \
            int s = sord[si];                                                     \
            gload_lds16(hz + (size_t)(row0 + s * 64 + srow) * K + (kt) * BK + cg * 8, \
                        (void*)&As[buf][s * 4096 + wid * 512]);                   \
        }                                                                         \
    } while (0)

#define LDSA(buf, rt, q) (*(const short8*)&As[buf][(rt) * BK + ((q) ^ ((rt) & 7)) * 8])
#define LDSB(buf, rt, q) (*(const short8*)&Bs[buf][(rt) * BK + ((q) ^ ((rt) & 7)) * 8])

    short8 a[4], b[4];
#define RD_A(CUR, HALF, KB)                                                       \
    { _Pragma("unroll")                                                           \
      for (int mi = 0; mi < 4; ++mi)                                              \
          a[mi] = LDSA(CUR, wm * 128 + (HALF) * 64 + mi * 16 + lm, (KB) + lk); }
#define RD_B(CUR, KB)                                                             \
    { _Pragma("unroll")                                                           \
      for (int ni = 0; ni < 4; ++ni)                                              \
          b[ni] = LDSB(CUR, wn * 64 + ni * 16 + lm, (KB) + lk); }
#define MM(BASE)                                                                  \
    { __builtin_amdgcn_s_setprio(1);                                              \
      _Pragma("unroll")                                                           \
      for (int mi = 0; mi < 4; ++mi)                                              \
          _Pragma("unroll")                                                       \
          for (int ni = 0; ni < 4; ++ni)                                          \
              acc[(BASE) + mi][ni] = __builtin_amdgcn_mfma_f32_16x16x32_bf16(     \
                  a[mi], b[ni], acc[(BASE) + mi][ni], 0, 0, 0);                   \
      __builtin_amdgcn_s_setprio(0); }

#define FENCE asm volatile("" ::: "memory")

    // TILE: P0 {stageB(next), wait W0, barrier, rdA(h0,kk0)+rdB(kk0), MFMA lo}
    //       P1 {stageA(next), wait W1, barrier, rdA(h1,kk0), MFMA hi}
    //       P2 {rdA(h0,kk1)+rdB(kk1), MFMA lo}   (no barrier: cur is read-only)
    //       P3 {rdA(h1,kk1), MFMA hi} ; lgkmcnt(0); barrier (gate buffer reuse)
#define TILE(CUR, NXT, DO_STAGE, KT, W0S, W1S)                                    \
    {                                                                             \
        if (DO_STAGE) STAGE_B(NXT, (KT) + 1);                                     \
        asm volatile("s_waitcnt vmcnt(" W0S ")" ::: "memory");                    \
        __builtin_amdgcn_s_barrier(); FENCE;                                      \
        RD_A(CUR, 0, 0) RD_B(CUR, 0) MM(0)                                        \
        if (DO_STAGE) STAGE_A(NXT, (KT) + 1);                                     \
        asm volatile("s_waitcnt vmcnt(" W1S ")" ::: "memory");                    \
        __builtin_amdgcn_s_barrier(); FENCE;                                      \
        RD_A(CUR, 1, 0) MM(4)                                                     \
        RD_A(CUR, 0, 4) RD_B(CUR, 4) MM(0)                                        \
        RD_A(CUR, 1, 4) MM(4)                                                     \
        asm volatile("s_waitcnt lgkmcnt(0)" ::: "memory");                        \
        __builtin_amdgcn_s_barrier(); FENCE;                                      \
    }

    // prologue: prime tiles 0 and 1 (16 loads/thread: B0, A0, B1, A1)
    STAGE_B(0, 0);
    STAGE_A(0, 0);
    STAGE_B(1, 1);
    STAGE_A(1, 1);

    TILE(0, 1, 0, 0, "10", "8")   // needs B0+A0_{02}: 16-6 ; then A0_{13}: leave B1,A1
    TILE(1, 0, 1, 1, "6",  "8")   // issue B2 then A2; waits leave next-tile loads in flight
    TILE(0, 1, 1, 2, "6",  "8")   // issue B3, A3
    TILE(1, 0, 0, 3, "2",  "0")

#undef TILE
#undef STAGE_A
#undef STAGE_B
#undef LDSA
#undef LDSB
#undef RD_A
#undef RD_B
#undef MM

    // Epilogue: exp + row sums. C/D: col = lane&15, row = (lane>>4)*4 + reg.
    const int lg = lane >> 4;
    #pragma unroll
    for (int mi = 0; mi < 8; ++mi) {
        float rs[4] = {0.f, 0.f, 0.f, 0.f};
        #pragma unroll
        for (int ni = 0; ni < 4; ++ni) {
            #pragma unroll
            for (int r = 0; r < 4; ++r) rs[r] += __expf(acc[mi][ni][r]);
        }
        #pragma unroll
        for (int r = 0; r < 4; ++r) {
            float s = rs[r];
            s += __shfl_xor(s, 1);
            s += __shfl_xor(s, 2);
            s += __shfl_xor(s, 4);
            s += __shfl_xor(s, 8);
            if (lm == 0)
                unsafeAtomicAdd(&row_acc[row0 + wm * 128 + mi * 16 + lg * 4 + r], s);
        }
    }

    // Last-block finalize: out = clip(log(acc) - g - log(B), -5, 15)
    __threadfence();
    __shared__ unsigned islast;
    if (tid == 0) {
        unsigned old = atomicAdd(done, 1u);
        islast = (old == gridDim.x * gridDim.y - 1) ? 1u : 0u;
    }
    __syncthreads();
    if (islast) {
        __threadfence();
        const float lb = logf((float)Brows);
        for (int i = tid; i < Brows; i += 512) {
            float av = __hip_atomic_load(&row_acc[i], __ATOMIC_RELAXED,
                                         __HIP_MEMORY_SCOPE_AGENT);
            float v = logf(av) - gvec[i] - lb;
            out[i] = fminf(fmaxf(v, -5.f), 15.f);
        }
    }
}

extern "C" void kernel_launch(void* const* d_in, const int* in_sizes, int n_in,
                              void* d_out, int out_size, void* d_ws, size_t ws_size,
                              hipStream_t stream) {
    const float* z       = (const float*)d_in[0];
    const float* t       = (const float*)d_in[1];
    const float* e       = (const float*)d_in[2];
    const float* log_tau = (const float*)d_in[3];
    const float* E       = (const float*)d_in[4];
    const float* L       = (const float*)d_in[5];
    float* out = (float*)d_out;

    const int B = in_sizes[1];   // 8192
    const int m = in_sizes[5];   // 256

    char* w = (char*)d_ws;
    __hip_bfloat16* hz = (__hip_bfloat16*)w;                 // B*m bf16
    __hip_bfloat16* hy = hz + (size_t)B * m;                 // B*m bf16
    float* ST   = (float*)(hy + (size_t)B * m);              // m*m f32
    float* g    = ST + (size_t)m * m;                        // B f32
    float* acc  = g + B;                                     // B f32
    unsigned* done = (unsigned*)(acc + B);                   // 1 u32

    suffix_kernel<<<m, 256, 0, stream>>>(E, ST, m);
    prep_kernel<<<B / 16, 256, 0, stream>>>(z, t, e, log_tau, E, L, ST, hz, hy, g, acc, done, B, m);
    dim3 grid2(B / BN, B / BM);
    gemm_lse_kernel<<<grid2, 512, 0, stream>>>(hz, hy, acc, g, out, done, B, m);
}

// Round 6
// 135.782 us; speedup vs baseline: 1.8175x; 1.8175x over previous
//
#include <hip/hip_runtime.h>
#include <hip/hip_bf16.h>

using short8  = __attribute__((ext_vector_type(8))) short;
using ushort8 = __attribute__((ext_vector_type(8))) unsigned short;
using f32x4   = __attribute__((ext_vector_type(4))) float;

#define BM 256
#define BN 256
#define BK 64
#define NKT 4   // K = 256 = NKT * BK

__device__ inline void gload_lds16(const void* g, void* lds) {
    __builtin_amdgcn_global_load_lds(
        (const __attribute__((address_space(1))) void*)g,
        (__attribute__((address_space(3))) void*)lds, 16, 0, 0);
}

// Kernel 0: suffix-sum table ST[k][j] = sum_{q>=k} E[j][q].
__global__ __launch_bounds__(256) void suffix_kernel(const float* __restrict__ E,
                                                     float* __restrict__ ST, int m) {
    int j = blockIdx.x;
    int k = threadIdx.x;
    int lane = k & 63, w = k >> 6;
    __shared__ float wtot[4];
    float v = (k < m) ? E[(size_t)j * m + k] : 0.f;
    #pragma unroll
    for (int off = 1; off < 64; off <<= 1) {
        float o = __shfl_down(v, off);
        if (lane + off < 64) v += o;
    }
    if (lane == 0) wtot[w] = v;
    __syncthreads();
    float add = 0.f;
    #pragma unroll
    for (int w2 = 0; w2 < 4; ++w2)
        if (w2 > w) add += wtot[w2];
    v += add;
    if (k < m) ST[(size_t)k * m + j] = v;
}

// Kernel 1: per-row prep. 16 lanes per row (4 rows/wave). Assumes m == 256, B % 16 == 0.
__global__ __launch_bounds__(256) void prep_kernel(
    const float* __restrict__ z, const float* __restrict__ t,
    const float* __restrict__ e, const float* __restrict__ log_tau,
    const float* __restrict__ E, const float* __restrict__ L,
    const float* __restrict__ ST,
    __hip_bfloat16* __restrict__ hz, __hip_bfloat16* __restrict__ hy,
    float* __restrict__ g, float* __restrict__ acc, int B, int m)
{
    const int tid = threadIdx.x;
    const int row = blockIdx.x * 16 + (tid >> 4);
    const int sub = tid & 15;

    float tv = t[row], ev = e[row];

    // searchsorted (side='left'): first idx with L[idx] >= t
    int lo = 0, hi = m;
    while (lo < hi) { int mid = (lo + hi) >> 1; if (L[mid] < tv) lo = mid + 1; else hi = mid; }
    int idx = lo;
    if (idx == 0) idx = 1;
    if (idx == m) idx = m - 1;

    float Llo = L[idx - 1], Lhi = L[idx];
    float w    = (tv - Llo) / (Lhi - Llo);
    float invd = 1.0f / (float)(m - idx);
    float invtau = expf(-0.5f * log_tau[0]);   // 1/sqrt(exp(log_tau))

    const int j0 = sub * 16;
    f32x4 zv[4], El4[4], Eh4[4], Sc4[4], yv[4];
    #pragma unroll
    for (int q = 0; q < 4; ++q) {
        zv[q]  = *(const f32x4*)&z [(size_t)row * m + j0 + q * 4];
        El4[q] = *(const f32x4*)&E [(size_t)(idx - 1) * m + j0 + q * 4];
        Eh4[q] = *(const f32x4*)&E [(size_t)idx * m + j0 + q * 4];
        Sc4[q] = *(const f32x4*)&ST[(size_t)idx * m + j0 + q * 4];
    }
    float ssy = 0.f, ssz = 0.f;
    #pragma unroll
    for (int q = 0; q < 4; ++q)
        #pragma unroll
        for (int p = 0; p < 4; ++p) {
            float yint = El4[q][p] + (Eh4[q][p] - El4[q][p]) * w;
            float ycen = Sc4[q][p] * invd;
            float y = yint * ev + ycen * (1.f - ev);
            yv[q][p] = y; ssy += y * y;
            ssz += zv[q][p] * zv[q][p];
        }
    #pragma unroll
    for (int off = 1; off < 16; off <<= 1) {
        ssy += __shfl_xor(ssy, off);
        ssz += __shfl_xor(ssz, off);
    }
    float sy = invtau / fmaxf(sqrtf(ssy), 1e-12f);
    float sz = invtau / fmaxf(sqrtf(ssz), 1e-12f);

    float gp = 0.f;
    ushort8 oy[2], oz[2];
    #pragma unroll
    for (int q = 0; q < 4; ++q)
        #pragma unroll
        for (int p = 0; p < 4; ++p) {
            float hyv = yv[q][p] * sy, hzv = zv[q][p] * sz;
            gp += hyv * hzv;
            __hip_bfloat16 hb = __float2bfloat16(hyv);
            __hip_bfloat16 zb = __float2bfloat16(hzv);
            oy[q >> 1][(q & 1) * 4 + p] = *reinterpret_cast<unsigned short*>(&hb);
            oz[q >> 1][(q & 1) * 4 + p] = *reinterpret_cast<unsigned short*>(&zb);
        }
    *(ushort8*)&hy[(size_t)row * m + j0]     = oy[0];
    *(ushort8*)&hy[(size_t)row * m + j0 + 8] = oy[1];
    *(ushort8*)&hz[(size_t)row * m + j0]     = oz[0];
    *(ushort8*)&hz[(size_t)row * m + j0 + 8] = oz[1];
    #pragma unroll
    for (int off = 1; off < 16; off <<= 1) gp += __shfl_xor(gp, off);
    if (sub == 0) { g[row] = gp; acc[row] = 0.f; }
}

// Kernel 2: fused sim = hz @ hy^T + exp + row partial sums.
// 256x256 tile, 8 waves (2M x 4N, per-wave 128x64), BK=64, dbuf 128KB LDS.
// 4 phases per K-tile, each {stage? ; counted vmcnt ; barrier ; ds_read ; setprio+MFMA ; barrier}.
// Counted waits: prologue primes tiles 0,1; tiles 1,2 stage tiles 2,3. Never drains mid-loop.
__global__ __launch_bounds__(512, 2) void gemm_lse_kernel(
    const __hip_bfloat16* __restrict__ hz, const __hip_bfloat16* __restrict__ hy,
    float* __restrict__ row_acc, int Brows, int K)
{
    __shared__ __hip_bfloat16 As[2][BM * BK];
    __shared__ __hip_bfloat16 Bs[2][BN * BK];

    const int tid  = threadIdx.x;
    const int wid  = tid >> 6;
    const int lane = tid & 63;
    const int wm   = wid >> 2;   // 0..1
    const int wn   = wid & 3;    // 0..3

    int bx = blockIdx.x, by = blockIdx.y;
    if (gridDim.x == 32 && gridDim.y == 32) {
        int orig = by * 32 + bx;
        int xcd = orig & 7, pos = orig >> 3;
        by = (xcd << 2) | (pos & 3);
        bx = pos >> 2;
    }
    const int row0 = by * BM, col0 = bx * BN;

    f32x4 acc[8][4];
    #pragma unroll
    for (int i = 0; i < 8; ++i)
        #pragma unroll
        for (int j = 0; j < 4; ++j)
            acc[i][j] = (f32x4){0.f, 0.f, 0.f, 0.f};

    const int srow = tid >> 3;            // 0..63
    const int c8   = tid & 7;
    const int cg   = c8 ^ (srow & 7);     // inverse-swizzled source chunk (rule 21)
    const int lm   = lane & 15, lk = lane >> 4;

    // B staged first (4 loads), then A in quarter order {0,2,1,3} so the quarters
    // phase 0 reads (s=0 and s=2) are the oldest A loads.
#define STAGE_B(buf, kt)                                                          \
    do {                                                                          \
        _Pragma("unroll")                                                         \
        for (int s = 0; s < 4; ++s)                                               \
            gload_lds16(hy + (size_t)(col0 + s * 64 + srow) * K + (kt) * BK + cg * 8, \
                        (void*)&Bs[buf][s * 4096 + wid * 512]);                   \
    } while (0)
#define STAGE_A(buf, kt)                                                          \
    do {                                                                          \
        const int sord[4] = {0, 2, 1, 3};                                         \
        _Pragma("unroll")                                                         \
        for (int si = 0; si < 4; ++si) {                                          \
            int s = sord[si];                                                     \
            gload_lds16(hz + (size_t)(row0 + s * 64 + srow) * K + (kt) * BK + cg * 8, \
                        (void*)&As[buf][s * 4096 + wid * 512]);                   \
        }                                                                         \
    } while (0)

#define LDSA(buf, rt, q) (*(const short8*)&As[buf][(rt) * BK + ((q) ^ ((rt) & 7)) * 8])
#define LDSB(buf, rt, q) (*(const short8*)&Bs[buf][(rt) * BK + ((q) ^ ((rt) & 7)) * 8])

    short8 a[4], b[4];
#define RD_A(CUR, HALF, KB)                                                       \
    { _Pragma("unroll")                                                           \
      for (int mi = 0; mi < 4; ++mi)                                              \
          a[mi] = LDSA(CUR, wm * 128 + (HALF) * 64 + mi * 16 + lm, (KB) + lk); }
#define RD_B(CUR, KB)                                                             \
    { _Pragma("unroll")                                                           \
      for (int ni = 0; ni < 4; ++ni)                                              \
          b[ni] = LDSB(CUR, wn * 64 + ni * 16 + lm, (KB) + lk); }
#define MM(BASE)                                                                  \
    { __builtin_amdgcn_s_setprio(1);                                              \
      _Pragma("unroll")                                                           \
      for (int mi = 0; mi < 4; ++mi)                                              \
          _Pragma("unroll")                                                       \
          for (int ni = 0; ni < 4; ++ni)                                          \
              acc[(BASE) + mi][ni] = __builtin_amdgcn_mfma_f32_16x16x32_bf16(     \
                  a[mi], b[ni], acc[(BASE) + mi][ni], 0, 0, 0);                   \
      __builtin_amdgcn_s_setprio(0); }

#define BAR  __builtin_amdgcn_s_barrier(); asm volatile("" ::: "memory")
#define WAITV(N) asm volatile("s_waitcnt vmcnt(" N ")" ::: "memory")

    // Per-phase shape (m201): {stage? ; vmcnt ; barrier ; ds_read ; MFMA(prio) ; barrier}
#define TILE(CUR, NXT, DO_STAGE, W0S, W1S, KT)                                    \
    {                                                                             \
        /* P0: kk=0, M-half 0 */                                                  \
        if (DO_STAGE) STAGE_B(NXT, (KT) + 1);                                     \
        WAITV(W0S); BAR;                                                          \
        RD_A(CUR, 0, 0) RD_B(CUR, 0)                                              \
        MM(0) BAR;                                                                \
        /* P1: kk=0, M-half 1 (reuse b) */                                        \
        if (DO_STAGE) STAGE_A(NXT, (KT) + 1);                                     \
        WAITV(W1S); BAR;                                                          \
        RD_A(CUR, 1, 0)                                                           \
        MM(4) BAR;                                                                \
        /* P2: kk=1, M-half 0 */                                                  \
        RD_A(CUR, 0, 4) RD_B(CUR, 4)                                              \
        MM(0) BAR;                                                                \
        /* P3: kk=1, M-half 1 */                                                  \
        RD_A(CUR, 1, 4)                                                           \
        MM(4)                                                                     \
        asm volatile("s_waitcnt lgkmcnt(0)" ::: "memory");                        \
        BAR;                                                                      \
    }

    // prologue: prime tiles 0 and 1 (per-wave issue order: B0, A0, B1, A1 = 16)
    STAGE_B(0, 0);
    STAGE_A(0, 0);
    STAGE_B(1, 1);
    STAGE_A(1, 1);

    // per-wave ledger: W = outstanding after retiring exactly what the phase needs
    TILE(0, 1, 0, "10", "8", 0)   // retire B0+A0{s0,s2} -> 10 ; then A0{s1,s3} -> 8
    TILE(1, 0, 1, "6",  "8", 1)   // +B2: 12, retire B1+A1{s0,s2} -> 6 ; +A2: 10, retire A1{s1,s3} -> 8
    TILE(0, 1, 1, "6",  "8", 2)   // +B3, +A3 likewise
    TILE(1, 0, 0, "2",  "0", 3)   // retire B3+A3{s0,s2} -> 2 ; then all -> 0

#undef TILE
#undef STAGE_A
#undef STAGE_B
#undef LDSA
#undef LDSB
#undef RD_A
#undef RD_B
#undef MM
#undef BAR
#undef WAITV

    // Epilogue: exp + row sums. C/D: col = lane&15, row = (lane>>4)*4 + reg.
    const int lg = lane >> 4;
    #pragma unroll
    for (int mi = 0; mi < 8; ++mi) {
        float rs[4] = {0.f, 0.f, 0.f, 0.f};
        #pragma unroll
        for (int ni = 0; ni < 4; ++ni) {
            #pragma unroll
            for (int r = 0; r < 4; ++r) rs[r] += __expf(acc[mi][ni][r]);
        }
        #pragma unroll
        for (int r = 0; r < 4; ++r) {
            float s = rs[r];
            s += __shfl_xor(s, 1);
            s += __shfl_xor(s, 2);
            s += __shfl_xor(s, 4);
            s += __shfl_xor(s, 8);
            if (lm == 0)
                unsafeAtomicAdd(&row_acc[row0 + wm * 128 + mi * 16 + lg * 4 + r], s);
        }
    }
}

// Kernel 3: out = clip(log(acc) - g - log(B), -5, 15)
__global__ void finalize_kernel(const float* __restrict__ acc, const float* __restrict__ g,
                                float* __restrict__ out, int B) {
    int i = blockIdx.x * 256 + threadIdx.x;
    if (i < B) {
        float v = logf(acc[i]) - g[i] - logf((float)B);
        out[i] = fminf(fmaxf(v, -5.f), 15.f);
    }
}

extern "C" void kernel_launch(void* const* d_in, const int* in_sizes, int n_in,
                              void* d_out, int out_size, void* d_ws, size_t ws_size,
                              hipStream_t stream) {
    const float* z       = (const float*)d_in[0];
    const float* t       = (const float*)d_in[1];
    const float* e       = (const float*)d_in[2];
    const float* log_tau = (const float*)d_in[3];
    const float* E       = (const float*)d_in[4];
    const float* L       = (const float*)d_in[5];
    float* out = (float*)d_out;

    const int B = in_sizes[1];   // 8192
    const int m = in_sizes[5];   // 256

    char* w = (char*)d_ws;
    __hip_bfloat16* hz = (__hip_bfloat16*)w;                 // B*m bf16
    __hip_bfloat16* hy = hz + (size_t)B * m;                 // B*m bf16
    float* ST   = (float*)(hy + (size_t)B * m);              // m*m f32
    float* g    = ST + (size_t)m * m;                        // B f32
    float* acc  = g + B;                                     // B f32

    suffix_kernel<<<m, 256, 0, stream>>>(E, ST, m);
    prep_kernel<<<B / 16, 256, 0, stream>>>(z, t, e, log_tau, E, L, ST, hz, hy, g, acc, B, m);
    dim3 grid2(B / BN, B / BM);
    gemm_lse_kernel<<<grid2, 512, 0, stream>>>(hz, hy, acc, B, m);
    finalize_kernel<<<(B + 255) / 256, 256, 0, stream>>>(acc, g, out, B);
}